// Round 3
// 114.055 us; speedup vs baseline: 1.0148x; 1.0148x over previous
//
#include <hip/hip_runtime.h>
#include <hip/hip_bf16.h>

// Problem constants (B=1)
#define CC   448   // channels
#define CGC  64    // key/query channels
#define MMM  7     // m groups
#define HWSZ 4096  // H*W
#define KK2  49    // K*K
#define GPH  32    // geometry-prior hidden

typedef __attribute__((ext_vector_type(8))) short   short8;   // 8 bf16 (4 VGPRs)
typedef __attribute__((ext_vector_type(4))) float   f32x4;
typedef __attribute__((ext_vector_type(4))) unsigned short us4;

__device__ __forceinline__ unsigned short f2b(float f) {
    union { __hip_bfloat16 h; unsigned short u; } cv;
    cv.h = __float2bfloat16(f);
    return cv.u;
}

// ---------------- Kernel 1: fused k+q GEMM, 128x16 tiles, 256 blocks -----
// C[128,4096] = [Wk;Wq] @ x. 256 blocks = 1 block/CU.
__global__ __launch_bounds__(256) void kq_mfma(
    const float* __restrict__ x,
    const float* __restrict__ Wk, const float* __restrict__ bk,
    const float* __restrict__ Wq, const float* __restrict__ bq,
    float* __restrict__ km, float* __restrict__ qm)
{
    __shared__ unsigned short As[4096];   // 8 KB [kg4][m128][j8]
    __shared__ unsigned short Bs[512];    // 1 KB [kg4][n16][j8]

    const int tid  = threadIdx.x;
    const int nT   = blockIdx.x * 16;
    const int lane = tid & 63;
    const int wid  = tid >> 6;
    const int wm   = wid * 32;
    const int l15  = lane & 15;
    const int l4   = lane >> 4;

    const int ar  = tid >> 3;         // 0..31: A row within rep
    const int ak  = tid & 7;          // which float4 of the 32-k chunk
    const int bkr = tid >> 3;         // 0..31: B k-row
    const int bn2 = tid & 7;          // 0..7: B float2 col group (16 cols)

    f32x4 acc[2];
    acc[0] = (f32x4){0.f, 0.f, 0.f, 0.f};
    acc[1] = (f32x4){0.f, 0.f, 0.f, 0.f};

    float4 a0 = *(const float4*)(Wk + (size_t)ar * CC + ak * 4);
    float4 a1 = *(const float4*)(Wk + (size_t)(ar + 32) * CC + ak * 4);
    float4 a2 = *(const float4*)(Wq + (size_t)ar * CC + ak * 4);
    float4 a3 = *(const float4*)(Wq + (size_t)(ar + 32) * CC + ak * 4);
    float2 b0 = *(const float2*)(x + (size_t)bkr * HWSZ + nT + bn2 * 2);

    for (int kt = 0; kt < 14; ++kt) {
        {
            int kg = ak >> 1, jo = (ak & 1) * 4;
            us4 w;
            w = (us4){ f2b(a0.x), f2b(a0.y), f2b(a0.z), f2b(a0.w) };
            *(us4*)&As[kg * 1024 + (ar +  0) * 8 + jo] = w;
            w = (us4){ f2b(a1.x), f2b(a1.y), f2b(a1.z), f2b(a1.w) };
            *(us4*)&As[kg * 1024 + (ar + 32) * 8 + jo] = w;
            w = (us4){ f2b(a2.x), f2b(a2.y), f2b(a2.z), f2b(a2.w) };
            *(us4*)&As[kg * 1024 + (ar + 64) * 8 + jo] = w;
            w = (us4){ f2b(a3.x), f2b(a3.y), f2b(a3.z), f2b(a3.w) };
            *(us4*)&As[kg * 1024 + (ar + 96) * 8 + jo] = w;
            int base = (bkr >> 3) * 128 + bn2 * 16 + (bkr & 7);
            Bs[base]     = f2b(b0.x);
            Bs[base + 8] = f2b(b0.y);
        }
        __syncthreads();
        if (kt < 13) {  // drain lands at NEXT barrier, overlapped by MFMA
            int ko = (kt + 1) * 32;
            a0 = *(const float4*)(Wk + (size_t)ar * CC + ko + ak * 4);
            a1 = *(const float4*)(Wk + (size_t)(ar + 32) * CC + ko + ak * 4);
            a2 = *(const float4*)(Wq + (size_t)ar * CC + ko + ak * 4);
            a3 = *(const float4*)(Wq + (size_t)(ar + 32) * CC + ko + ak * 4);
            b0 = *(const float2*)(x + (size_t)(ko + bkr) * HWSZ + nT + bn2 * 2);
        }
        short8 fa0 = *(short8*)&As[l4 * 1024 + (wm + l15) * 8];
        short8 fa1 = *(short8*)&As[l4 * 1024 + (wm + 16 + l15) * 8];
        short8 fb0 = *(short8*)&Bs[l4 * 128 + l15 * 8];
        acc[0] = __builtin_amdgcn_mfma_f32_16x16x32_bf16(fa0, fb0, acc[0], 0, 0, 0);
        acc[1] = __builtin_amdgcn_mfma_f32_16x16x32_bf16(fa1, fb0, acc[1], 0, 0, 0);
        __syncthreads();
    }
    const bool isK = (wid < 2);
    float*       Cd   = isK ? km : qm;
    const float* bias = isK ? bk : bq;
    const int rbase = wm & 63;
    #pragma unroll
    for (int wm2 = 0; wm2 < 2; ++wm2)
        #pragma unroll
        for (int r = 0; r < 4; ++r) {
            int row = rbase + wm2 * 16 + l4 * 4 + r;
            int col = nT + l15;
            Cd[(size_t)row * HWSZ + col] = acc[wm2][r] + bias[row];
        }
}

// ---------------- Kernel 3: fconv GEMM, 64x32 tiles (f32 pre, baseline) --
__global__ __launch_bounds__(256) void fconv_mfma(
    const float* __restrict__ pre,
    const float* __restrict__ Wf, const float* __restrict__ bfv,
    float* __restrict__ out)
{
    __shared__ unsigned short As[2048];   // 4 KB [kg4][m64][j8]
    __shared__ unsigned short Bs[1024];   // 2 KB [kg4][n32][j8]

    const int tid  = threadIdx.x;
    const int nT   = blockIdx.x * 32;
    const int oT   = blockIdx.y * 64;
    const int lane = tid & 63;
    const int wid  = tid >> 6;
    const int l15  = lane & 15;
    const int l4   = lane >> 4;

    const int ar  = tid >> 3;
    const int ak  = tid & 7;
    const int bkr = tid >> 3;
    const int bn4 = tid & 7;

    const float* __restrict__ A = Wf + (size_t)oT * CC;

    f32x4 acc[2];
    acc[0] = (f32x4){0.f, 0.f, 0.f, 0.f};
    acc[1] = (f32x4){0.f, 0.f, 0.f, 0.f};

    float4 a0 = *(const float4*)(A + (size_t)ar * CC + ak * 4);
    float4 a1 = *(const float4*)(A + (size_t)(ar + 32) * CC + ak * 4);
    float4 b0 = *(const float4*)(pre + (size_t)bkr * HWSZ + nT + bn4 * 4);

    for (int kt = 0; kt < 14; ++kt) {
        {
            int kg = ak >> 1, jo = (ak & 1) * 4;
            us4 w;
            w = (us4){ f2b(a0.x), f2b(a0.y), f2b(a0.z), f2b(a0.w) };
            *(us4*)&As[kg * 512 + (ar +  0) * 8 + jo] = w;
            w = (us4){ f2b(a1.x), f2b(a1.y), f2b(a1.z), f2b(a1.w) };
            *(us4*)&As[kg * 512 + (ar + 32) * 8 + jo] = w;
            int base = (bkr >> 3) * 256 + bn4 * 32 + (bkr & 7);
            Bs[base]      = f2b(b0.x);
            Bs[base + 8]  = f2b(b0.y);
            Bs[base + 16] = f2b(b0.z);
            Bs[base + 24] = f2b(b0.w);
        }
        __syncthreads();
        if (kt < 13) {
            int ko = (kt + 1) * 32;
            a0 = *(const float4*)(A + (size_t)ar * CC + ko + ak * 4);
            a1 = *(const float4*)(A + (size_t)(ar + 32) * CC + ko + ak * 4);
            b0 = *(const float4*)(pre + (size_t)(ko + bkr) * HWSZ + nT + bn4 * 4);
        }
        short8 fa  = *(short8*)&As[l4 * 512 + (wid * 16 + l15) * 8];
        short8 fb0 = *(short8*)&Bs[l4 * 256 + l15 * 8];
        short8 fb1 = *(short8*)&Bs[l4 * 256 + (16 + l15) * 8];
        acc[0] = __builtin_amdgcn_mfma_f32_16x16x32_bf16(fa, fb0, acc[0], 0, 0, 0);
        acc[1] = __builtin_amdgcn_mfma_f32_16x16x32_bf16(fa, fb1, acc[1], 0, 0, 0);
        __syncthreads();
    }
    #pragma unroll
    for (int wn2 = 0; wn2 < 2; ++wn2)
        #pragma unroll
        for (int r = 0; r < 4; ++r) {
            int row = oT + wid * 16 + l4 * 4 + r;
            int col = nT + wn2 * 16 + l15;
            out[(size_t)row * HWSZ + col] = acc[wn2][r] + bfv[row];
        }
}

// ---------------- Kernel 2: attention, all-pages-resident, weird-view ----
// Exact baseline (verified) indexing: n = lp*49 + t, p = n>>12, l = n&4095,
// value = page[l + (di-3)*64 + (dj-3)] with j-wrap masking; linear pages
// with zero guard bands handle row over/underflow. All 8 pages (km + 7 x
// channels) resident in LDS at once -> 1 barrier, single fused 49-tap pass
// (no max-subtraction: ratios identical), denominator + 7 numerators.
// Taps processed in pairs sharing one segment base (merges to ds_read2);
// the single mis-segmented tap (odd ts < 49, <=48 lanes per g) is repaired
// by a closed-form subtract/add fixup.
#define GLO 196
#define GHI 260
#define PGW (GLO + HWSZ + GHI)   // 4552 words per page
#define NPG 8                    // km + 7 x pages  (142.4 KB LDS)

__global__ __launch_bounds__(1024, 4) void attn_kernel(
    const float* __restrict__ km, const float* __restrict__ qm,
    const float* __restrict__ x,
    const float* __restrict__ gw1, const float* __restrict__ gb1,
    const float* __restrict__ gw2, const float* __restrict__ gb2,
    float* __restrict__ pre)
{
    __shared__ __align__(16) float sm[NPG * PGW];
    __shared__ float gpk_s[KK2];

    const int tid = threadIdx.x;
    const int g   = blockIdx.y;
    const int lp  = blockIdx.x * 1024 + tid;

    // zero guard bands: 49 + 65 float4 per page, 912 total
    if (tid < NPG * 114) {
        int page = tid / 114;
        int r    = tid - page * 114;
        int w    = (r < 49) ? r * 4 : (GLO + HWSZ + (r - 49) * 4);
        *(float4*)&sm[page * PGW + w] = (float4){0.f, 0.f, 0.f, 0.f};
    }
    // stage payloads: page 0 = km row g, pages 1..7 = x channel m*64+g
    {
        const float4* s0 = (const float4*)(km + (size_t)g * HWSZ);
        *(float4*)&sm[GLO + tid * 4] = s0[tid];
        #pragma unroll
        for (int m = 0; m < MMM; ++m) {
            const float4* sx = (const float4*)(x + (size_t)(m * CGC + g) * HWSZ);
            *(float4*)&sm[(m + 1) * PGW + GLO + tid * 4] = sx[tid];
        }
    }
    // fused geometry prior, row g (49 values)
    if (tid < KK2) {
        int di = tid / 7, dj = tid - di * 7;
        float xp = (float)(dj - 3);
        float yp = (float)(3 - di);
        float a2 = gb2[g];
        #pragma unroll
        for (int j = 0; j < GPH; ++j) {
            float h = fmaxf(gw1[j * 2 + 0] * xp + gw1[j * 2 + 1] * yp + gb1[j], 0.f);
            a2 = fmaf(gw2[g * GPH + j], h, a2);
        }
        gpk_s[tid] = a2;
    }

    // q center tap under the weird view: n = lp*49 + 24
    float qc;
    {
        int nc = lp * KK2 + 24;
        int pc = nc >> 12, lc = nc & 4095;
        int dic = (pc * 37) >> 8, djc = pc - dic * 7;
        int i = (lc >> 6) + dic - 3, j = (lc & 63) + djc - 3;
        bool ok = ((unsigned)i < 64u) && ((unsigned)j < 64u);
        qc = ok ? qm[(size_t)g * HWSZ + i * 64 + j] : 0.f;
    }

    // per-thread segment constants (taps span <=2 p-segments)
    const int n0 = lp * KK2;
    const int p0 = n0 >> 12;
    const int l0 = n0 & 4095;
    const int ts = ((p0 + 1) << 12) - n0;          // taps in segment 0 (>=1)
    const int di0 = (p0 * 37) >> 8, dj0 = p0 - di0 * 7;
    const int p1  = p0 + 1;
    const int di1 = (p1 * 37) >> 8, dj1 = p1 - di1 * 7;
    const int dm0 = dj0 - 3, dm1 = dj1 - 3;
    const int B0 = GLO + l0 + (di0 - 3) * 64 + dm0;
    const int B1 = GLO + l0 - HWSZ + (di1 - 3) * 64 + dm1;
    // unified j-mask: bad <=> ((c + t) & 63) < w
    const int c0 = l0 + (dm0 > 0 ? dm0 : 0), w0 = (dm0 < 0) ? -dm0 : dm0;
    const int c1 = l0 + (dm1 > 0 ? dm1 : 0), w1 = (dm1 < 0) ? -dm1 : dm1;

    __syncthreads();   // everything staged; only barrier in the kernel

    float d = 0.f;
    float acc[MMM];
    #pragma unroll
    for (int m = 0; m < MMM; ++m) acc[m] = 0.f;

    // 24 tap-pairs, one base/mask select per pair
    #pragma unroll
    for (int tp = 0; tp < 24; ++tp) {
        const int t0 = 2 * tp, t1 = t0 + 1;
        const bool s1 = (t1 >= ts);
        const int bb = s1 ? B1 : B0;
        const int cc = s1 ? c1 : c0;
        const int ww = s1 ? w1 : w0;
        float kv0 = sm[bb + t0];
        float kv1 = sm[bb + t1];
        const bool bad0 = (((cc + t0) & 63) < ww);
        const bool bad1 = (((cc + t1) & 63) < ww);
        kv0 = bad0 ? 0.f : kv0;
        kv1 = bad1 ? 0.f : kv1;
        const float e0 = __expf(fmaf(kv0, qc, gpk_s[t0]));
        const float e1 = __expf(fmaf(kv1, qc, gpk_s[t1]));
        d += e0 + e1;
        const float em0 = bad0 ? 0.f : e0;
        const float em1 = bad1 ? 0.f : e1;
        #pragma unroll
        for (int m = 0; m < MMM; ++m) {
            const int ob = bb + (m + 1) * PGW;
            acc[m] = fmaf(em1, sm[ob + t1], fmaf(em0, sm[ob + t0], acc[m]));
        }
    }
    { // tap 48 singleton
        const bool s1 = (48 >= ts);
        const int bb = s1 ? B1 : B0;
        const int cc = s1 ? c1 : c0;
        const int ww = s1 ? w1 : w0;
        float kv = sm[bb + 48];
        const bool bad = (((cc + 48) & 63) < ww);
        kv = bad ? 0.f : kv;
        const float e = __expf(fmaf(kv, qc, gpk_s[48]));
        d += e;
        const float em = bad ? 0.f : e;
        #pragma unroll
        for (int m = 0; m < MMM; ++m)
            acc[m] = fmaf(em, sm[bb + (m + 1) * PGW + 48], acc[m]);
    }
    // fixup: odd ts < 49 -> tap ts-1 was read with seg1 base; swap its
    // contribution for the correct seg0 one (deterministic re-reads).
    if (ts < 49 && (ts & 1)) {
        const int tw = ts - 1;
        const float gw = gpk_s[tw];
        float kw = sm[B1 + tw];                       // what main loop used
        const bool bw = (((c1 + tw) & 63) < w1);
        kw = bw ? 0.f : kw;
        const float ew  = __expf(fmaf(kw, qc, gw));
        const float emw = bw ? 0.f : ew;
        float kr = sm[B0 + tw];                       // correct seg0 value
        const bool br = (((c0 + tw) & 63) < w0);
        kr = br ? 0.f : kr;
        const float er  = __expf(fmaf(kr, qc, gw));
        const float emr = br ? 0.f : er;
        d += er - ew;
        #pragma unroll
        for (int m = 0; m < MMM; ++m)
            acc[m] += emr * sm[B0 + (m + 1) * PGW + tw]
                    - emw * sm[B1 + (m + 1) * PGW + tw];
    }

    const float inv = 1.f / d;
    #pragma unroll
    for (int m = 0; m < MMM; ++m)
        pre[(size_t)(m * CGC + g) * HWSZ + lp] = acc[m] * inv;
}

extern "C" void kernel_launch(void* const* d_in, const int* in_sizes, int n_in,
                              void* d_out, int out_size, void* d_ws, size_t ws_size,
                              hipStream_t stream) {
    const float* x   = (const float*)d_in[0];
    const float* Wk  = (const float*)d_in[1];
    const float* bk  = (const float*)d_in[2];
    const float* Wq  = (const float*)d_in[3];
    const float* bq  = (const float*)d_in[4];
    const float* gw1 = (const float*)d_in[5];
    const float* gb1 = (const float*)d_in[6];
    const float* gw2 = (const float*)d_in[7];
    const float* gb2 = (const float*)d_in[8];
    const float* Wf  = (const float*)d_in[9];
    const float* bfv = (const float*)d_in[10];
    float* out = (float*)d_out;

    float* km  = (float*)d_ws;             // 64*4096
    float* qm  = km + CGC * HWSZ;          // 64*4096
    float* pre = qm + CGC * HWSZ;          // 448*4096

    kq_mfma    <<<dim3(256),    256, 0, stream>>>(x, Wk, bk, Wq, bq, km, qm);
    attn_kernel<<<dim3(4, CGC), 1024, 0, stream>>>(km, qm, x, gw1, gb1, gw2, gb2, pre);
    fconv_mfma <<<dim3(128, 7), 256, 0, stream>>>(pre, Wf, bfv, out);
}

// Round 5
// 108.033 us; speedup vs baseline: 1.0714x; 1.0557x over previous
//
#include <hip/hip_runtime.h>
#include <hip/hip_bf16.h>

// Problem constants (B=1)
#define CC   448   // channels
#define CGC  64    // key/query channels
#define MMM  7     // m groups
#define HWSZ 4096  // H*W
#define KK2  49    // K*K
#define GPH  32    // geometry-prior hidden

typedef __attribute__((ext_vector_type(8))) short   short8;   // 8 bf16 (4 VGPRs)
typedef __attribute__((ext_vector_type(4))) float   f32x4;
typedef __attribute__((ext_vector_type(4))) unsigned short us4;

__device__ __forceinline__ unsigned short f2b(float f) {
    union { __hip_bfloat16 h; unsigned short u; } cv;
    cv.h = __float2bfloat16(f);
    return cv.u;
}

// ---------------- Kernel 1: fused k+q GEMM, single-shot staging ----------
// C[128,4096] = [Wk;Wq] @ x, 256 blocks x 1024 thr (16 waves). All of K=448
// staged in LDS at once (A 112 KB + B 14 KB): 1 load burst, 1 barrier,
// 7 MFMAs/wave with split-K over wave pairs, LDS reduce, store.
// Replaces the old 14-iteration / 28-barrier latency chain.
__global__ __launch_bounds__(1024, 4) void kq_mfma(
    const float* __restrict__ x,
    const float* __restrict__ Wk, const float* __restrict__ bk,
    const float* __restrict__ Wq, const float* __restrict__ bq,
    float* __restrict__ km, float* __restrict__ qm)
{
    __shared__ unsigned short As[57344];  // [kg56][m128][j8]  112 KB
    __shared__ unsigned short Bs[7168];   // [kg56][n16][j8]    14 KB
    __shared__ float         red[2048];   // 8 tiles x 256       8 KB

    const int tid  = threadIdx.x;
    const int nT   = blockIdx.x * 16;
    const int lane = tid & 63;
    const int wid  = tid >> 6;
    const int l15  = lane & 15;
    const int l4   = lane >> 4;

    // stage A: 128 rows x 112 float4 = 14336 f4, 14/thread, coalesced
    #pragma unroll
    for (int i = 0; i < 14; ++i) {
        int idx = tid + i * 1024;
        int row = idx / 112;              // 0..127
        int c   = idx - row * 112;        // f4 within row
        const float* src = (row < 64) ? (Wk + (size_t)row * CC)
                                      : (Wq + (size_t)(row - 64) * CC);
        float4 v = *(const float4*)(src + c * 4);
        int kg = c >> 1, jo = (c & 1) * 4;
        *(us4*)&As[kg * 1024 + row * 8 + jo] =
            (us4){ f2b(v.x), f2b(v.y), f2b(v.z), f2b(v.w) };
    }
    // stage B: 448 rows x 4 float4 = 1792 f4
    #pragma unroll
    for (int i = 0; i < 2; ++i) {
        int idx = tid + i * 1024;
        if (idx < 1792) {
            int row = idx >> 2, c4 = idx & 3;
            float4 v = *(const float4*)(x + (size_t)row * HWSZ + nT + c4 * 4);
            int kg = row >> 3, j = row & 7;
            int b  = kg * 128 + c4 * 32 + j;
            Bs[b]      = f2b(v.x);
            Bs[b + 8]  = f2b(v.y);
            Bs[b + 16] = f2b(v.z);
            Bs[b + 24] = f2b(v.w);
        }
    }
    __syncthreads();

    // wave w: m-tile (w&7)*16, K-half (w>>3)*224
    const int mt = (wid & 7) * 16;
    const int kh = wid >> 3;
    f32x4 acc = (f32x4){0.f, 0.f, 0.f, 0.f};
    #pragma unroll
    for (int i = 0; i < 7; ++i) {
        int K4 = kh * 28 + i * 4;
        short8 fa = *(short8*)&As[(K4 + l4) * 1024 + (mt + l15) * 8];
        short8 fb = *(short8*)&Bs[(K4 + l4) * 128 + l15 * 8];
        acc = __builtin_amdgcn_mfma_f32_16x16x32_bf16(fa, fb, acc, 0, 0, 0);
    }
    if (kh == 1)
        *(f32x4*)&red[(wid & 7) * 256 + lane * 4] = acc;
    __syncthreads();
    if (kh == 0) {
        f32x4 o = *(f32x4*)&red[(wid & 7) * 256 + lane * 4];
        const bool isK = (mt < 64);
        float*       Cd   = isK ? km : qm;
        const float* bias = isK ? bk : bq;
        const int rb = (mt & 63) + l4 * 4;
        #pragma unroll
        for (int r = 0; r < 4; ++r) {
            int row = rb + r;
            Cd[(size_t)row * HWSZ + nT + l15] = acc[r] + o[r] + bias[row];
        }
    }
}

// ---------------- Kernel 3: fconv GEMM, single-shot staging --------------
// out[448,4096] = Wf @ pre. 256 blocks x 1024 thr: block = (4 row-tiles of
// 112) x (64 col-tiles of 64). A 112x448 (100 KB) + B 448x64 (57 KB) staged
// once -> 1 barrier, 14 waves x 28 MFMAs, store. (154 KB LDS, 1 block/CU.)
__global__ __launch_bounds__(1024, 4) void fconv_mfma(
    const float* __restrict__ pre,
    const float* __restrict__ Wf, const float* __restrict__ bfv,
    float* __restrict__ out)
{
    __shared__ unsigned short As[50176];  // [kg56][m112][j8] 100352 B
    __shared__ unsigned short Bs[28672];  // [kg56][n64][j8]   57344 B

    const int tid  = threadIdx.x;
    const int bid  = blockIdx.x;          // 0..255
    const int nT   = (bid >> 2) * 64;
    const int oT   = (bid & 3) * 112;
    const int lane = tid & 63;
    const int wid  = tid >> 6;
    const int l15  = lane & 15;
    const int l4   = lane >> 4;

    // stage A: 112 rows x 112 f4 = 12544 f4
    #pragma unroll
    for (int i = 0; i < 13; ++i) {
        int idx = tid + i * 1024;
        if (idx < 12544) {
            int row = idx / 112;
            int c   = idx - row * 112;
            float4 v = *(const float4*)(Wf + (size_t)(oT + row) * CC + c * 4);
            int kg = c >> 1, jo = (c & 1) * 4;
            *(us4*)&As[kg * 896 + row * 8 + jo] =
                (us4){ f2b(v.x), f2b(v.y), f2b(v.z), f2b(v.w) };
        }
    }
    // stage B: 448 rows x 16 f4 = 7168 f4 (exactly 7/thread)
    #pragma unroll
    for (int i = 0; i < 7; ++i) {
        int idx = tid + i * 1024;
        int row = idx >> 4, c4 = idx & 15;
        float4 v = *(const float4*)(pre + (size_t)row * HWSZ + nT + c4 * 4);
        int kg = row >> 3, j = row & 7;
        int b  = kg * 512 + c4 * 32 + j;
        Bs[b]      = f2b(v.x);
        Bs[b + 8]  = f2b(v.y);
        Bs[b + 16] = f2b(v.z);
        Bs[b + 24] = f2b(v.w);
    }
    __syncthreads();

    if (wid < 14) {
        const int mt = (wid % 7) * 16;
        const int np = wid / 7;           // n-pair: covers n-tiles {2np, 2np+1}
        f32x4 a0 = (f32x4){0.f, 0.f, 0.f, 0.f};
        f32x4 a1 = (f32x4){0.f, 0.f, 0.f, 0.f};
        #pragma unroll
        for (int i = 0; i < 14; ++i) {
            int K4 = i * 4;
            short8 fa  = *(short8*)&As[(K4 + l4) * 896 + (mt + l15) * 8];
            short8 fb0 = *(short8*)&Bs[(K4 + l4) * 512 + (np * 32 + l15) * 8];
            short8 fb1 = *(short8*)&Bs[(K4 + l4) * 512 + (np * 32 + 16 + l15) * 8];
            a0 = __builtin_amdgcn_mfma_f32_16x16x32_bf16(fa, fb0, a0, 0, 0, 0);
            a1 = __builtin_amdgcn_mfma_f32_16x16x32_bf16(fa, fb1, a1, 0, 0, 0);
        }
        #pragma unroll
        for (int wn2 = 0; wn2 < 2; ++wn2) {
            const f32x4 a = wn2 ? a1 : a0;
            #pragma unroll
            for (int r = 0; r < 4; ++r) {
                int row = oT + mt + l4 * 4 + r;
                int col = nT + np * 32 + wn2 * 16 + l15;
                out[(size_t)row * HWSZ + col] = a[r] + bfv[row];
            }
        }
    }
}

// ---------------- Kernel 2: attention (verified round-3 version) ---------
#define GLO 196
#define GHI 260
#define PGW (GLO + HWSZ + GHI)   // 4552 words per page
#define NPG 8                    // km + 7 x pages  (142.4 KB LDS)

__global__ __launch_bounds__(1024, 4) void attn_kernel(
    const float* __restrict__ km, const float* __restrict__ qm,
    const float* __restrict__ x,
    const float* __restrict__ gw1, const float* __restrict__ gb1,
    const float* __restrict__ gw2, const float* __restrict__ gb2,
    float* __restrict__ pre)
{
    __shared__ __align__(16) float sm[NPG * PGW];
    __shared__ float gpk_s[KK2];

    const int tid = threadIdx.x;
    const int g   = blockIdx.y;
    const int lp  = blockIdx.x * 1024 + tid;

    // zero guard bands: 49 + 65 float4 per page, 912 total
    if (tid < NPG * 114) {
        int page = tid / 114;
        int r    = tid - page * 114;
        int w    = (r < 49) ? r * 4 : (GLO + HWSZ + (r - 49) * 4);
        *(float4*)&sm[page * PGW + w] = (float4){0.f, 0.f, 0.f, 0.f};
    }
    // stage payloads: page 0 = km row g, pages 1..7 = x channel m*64+g
    {
        const float4* s0 = (const float4*)(km + (size_t)g * HWSZ);
        *(float4*)&sm[GLO + tid * 4] = s0[tid];
        #pragma unroll
        for (int m = 0; m < MMM; ++m) {
            const float4* sx = (const float4*)(x + (size_t)(m * CGC + g) * HWSZ);
            *(float4*)&sm[(m + 1) * PGW + GLO + tid * 4] = sx[tid];
        }
    }
    // fused geometry prior, row g (49 values)
    if (tid < KK2) {
        int di = tid / 7, dj = tid - di * 7;
        float xp = (float)(dj - 3);
        float yp = (float)(3 - di);
        float a2 = gb2[g];
        #pragma unroll
        for (int j = 0; j < GPH; ++j) {
            float h = fmaxf(gw1[j * 2 + 0] * xp + gw1[j * 2 + 1] * yp + gb1[j], 0.f);
            a2 = fmaf(gw2[g * GPH + j], h, a2);
        }
        gpk_s[tid] = a2;
    }

    // q center tap under the weird view: n = lp*49 + 24
    float qc;
    {
        int nc = lp * KK2 + 24;
        int pc = nc >> 12, lc = nc & 4095;
        int dic = (pc * 37) >> 8, djc = pc - dic * 7;
        int i = (lc >> 6) + dic - 3, j = (lc & 63) + djc - 3;
        bool ok = ((unsigned)i < 64u) && ((unsigned)j < 64u);
        qc = ok ? qm[(size_t)g * HWSZ + i * 64 + j] : 0.f;
    }

    // per-thread segment constants (taps span <=2 p-segments)
    const int n0 = lp * KK2;
    const int p0 = n0 >> 12;
    const int l0 = n0 & 4095;
    const int ts = ((p0 + 1) << 12) - n0;          // taps in segment 0 (>=1)
    const int di0 = (p0 * 37) >> 8, dj0 = p0 - di0 * 7;
    const int p1  = p0 + 1;
    const int di1 = (p1 * 37) >> 8, dj1 = p1 - di1 * 7;
    const int dm0 = dj0 - 3, dm1 = dj1 - 3;
    const int B0 = GLO + l0 + (di0 - 3) * 64 + dm0;
    const int B1 = GLO + l0 - HWSZ + (di1 - 3) * 64 + dm1;
    // unified j-mask: bad <=> ((c + t) & 63) < w
    const int c0 = l0 + (dm0 > 0 ? dm0 : 0), w0 = (dm0 < 0) ? -dm0 : dm0;
    const int c1 = l0 + (dm1 > 0 ? dm1 : 0), w1 = (dm1 < 0) ? -dm1 : dm1;

    __syncthreads();   // everything staged; only barrier in the kernel

    float d = 0.f;
    float acc[MMM];
    #pragma unroll
    for (int m = 0; m < MMM; ++m) acc[m] = 0.f;

    // 24 tap-pairs, one base/mask select per pair
    #pragma unroll
    for (int tp = 0; tp < 24; ++tp) {
        const int t0 = 2 * tp, t1 = t0 + 1;
        const bool s1 = (t1 >= ts);
        const int bb = s1 ? B1 : B0;
        const int cc = s1 ? c1 : c0;
        const int ww = s1 ? w1 : w0;
        float kv0 = sm[bb + t0];
        float kv1 = sm[bb + t1];
        const bool bad0 = (((cc + t0) & 63) < ww);
        const bool bad1 = (((cc + t1) & 63) < ww);
        kv0 = bad0 ? 0.f : kv0;
        kv1 = bad1 ? 0.f : kv1;
        const float e0 = __expf(fmaf(kv0, qc, gpk_s[t0]));
        const float e1 = __expf(fmaf(kv1, qc, gpk_s[t1]));
        d += e0 + e1;
        const float em0 = bad0 ? 0.f : e0;
        const float em1 = bad1 ? 0.f : e1;
        #pragma unroll
        for (int m = 0; m < MMM; ++m) {
            const int ob = bb + (m + 1) * PGW;
            acc[m] = fmaf(em1, sm[ob + t1], fmaf(em0, sm[ob + t0], acc[m]));
        }
    }
    { // tap 48 singleton
        const bool s1 = (48 >= ts);
        const int bb = s1 ? B1 : B0;
        const int cc = s1 ? c1 : c0;
        const int ww = s1 ? w1 : w0;
        float kv = sm[bb + 48];
        const bool bad = (((cc + 48) & 63) < ww);
        kv = bad ? 0.f : kv;
        const float e = __expf(fmaf(kv, qc, gpk_s[48]));
        d += e;
        const float em = bad ? 0.f : e;
        #pragma unroll
        for (int m = 0; m < MMM; ++m)
            acc[m] = fmaf(em, sm[bb + (m + 1) * PGW + 48], acc[m]);
    }
    // fixup: odd ts < 49 -> tap ts-1 was read with seg1 base; swap its
    // contribution for the correct seg0 one (deterministic re-reads).
    if (ts < 49 && (ts & 1)) {
        const int tw = ts - 1;
        const float gw = gpk_s[tw];
        float kw = sm[B1 + tw];                       // what main loop used
        const bool bw = (((c1 + tw) & 63) < w1);
        kw = bw ? 0.f : kw;
        const float ew  = __expf(fmaf(kw, qc, gw));
        const float emw = bw ? 0.f : ew;
        float kr = sm[B0 + tw];                       // correct seg0 value
        const bool br = (((c0 + tw) & 63) < w0);
        kr = br ? 0.f : kr;
        const float er  = __expf(fmaf(kr, qc, gw));
        const float emr = br ? 0.f : er;
        d += er - ew;
        #pragma unroll
        for (int m = 0; m < MMM; ++m)
            acc[m] += emr * sm[B0 + (m + 1) * PGW + tw]
                    - emw * sm[B1 + (m + 1) * PGW + tw];
    }

    const float inv = 1.f / d;
    #pragma unroll
    for (int m = 0; m < MMM; ++m)
        pre[(size_t)(m * CGC + g) * HWSZ + lp] = acc[m] * inv;
}

extern "C" void kernel_launch(void* const* d_in, const int* in_sizes, int n_in,
                              void* d_out, int out_size, void* d_ws, size_t ws_size,
                              hipStream_t stream) {
    const float* x   = (const float*)d_in[0];
    const float* Wk  = (const float*)d_in[1];
    const float* bk  = (const float*)d_in[2];
    const float* Wq  = (const float*)d_in[3];
    const float* bq  = (const float*)d_in[4];
    const float* gw1 = (const float*)d_in[5];
    const float* gb1 = (const float*)d_in[6];
    const float* gw2 = (const float*)d_in[7];
    const float* gb2 = (const float*)d_in[8];
    const float* Wf  = (const float*)d_in[9];
    const float* bfv = (const float*)d_in[10];
    float* out = (float*)d_out;

    float* km  = (float*)d_ws;             // 64*4096
    float* qm  = km + CGC * HWSZ;          // 64*4096
    float* pre = qm + CGC * HWSZ;          // 448*4096

    kq_mfma    <<<dim3(256),    1024, 0, stream>>>(x, Wk, bk, Wq, bq, km, qm);
    attn_kernel<<<dim3(4, CGC), 1024, 0, stream>>>(km, qm, x, gw1, gb1, gw2, gb2, pre);
    fconv_mfma <<<dim3(256),    1024, 0, stream>>>(pre, Wf, bfv, out);
}